// Round 3
// baseline (896.810 us; speedup 1.0000x reference)
//
#include <hip/hip_runtime.h>
#include <math.h>

// NSVQ: N=262144 rows, D=64, K=1024 codebooks.
// d_out (fp32): [N*D] quantized | [1] perplexity | [K] counts_new.
//
// argmin_k(||c||^2 - 2 x.c) via bf16 hi/lo-split MFMA (hi*hi + lo*hi + hi*lo),
// codebook chunks staged in LDS (global_load_lds w=16, u-major swizzle so
// B-frag ds_read_b128 is bank-conflict-free), epilogue fused (exact fp32
// residual recompute + NSVQ output + histogram).

#define NROWS 262144
#define DIM 64
#define KCODES 1024
#define ND ((size_t)NROWS * DIM)

typedef __attribute__((ext_vector_type(8))) short bf16x8;   // 8 bf16, 4 VGPRs
typedef __attribute__((ext_vector_type(4))) float f32x4;

__device__ inline short f2bf(float f) {             // RNE fp32 -> bf16
    unsigned u = __builtin_bit_cast(unsigned, f);
    unsigned r = (u + 0x7FFFu + ((u >> 16) & 1u)) >> 16;
    return (short)r;
}
__device__ inline float bf2f(short h) {
    unsigned u = ((unsigned)(unsigned short)h) << 16;
    return __builtin_bit_cast(float, u);
}

typedef const __attribute__((address_space(1))) void* as1p;
typedef __attribute__((address_space(3))) void* as3p;
__device__ inline void gl_lds16(const void* g, void* l) {
    __builtin_amdgcn_global_load_lds((as1p)g, (as3p)l, 16, 0, 0);
}

// --- prep: hi/lo bf16 split + fp32 norms; 16 lanes per code --------------
__global__ __launch_bounds__(256) void nsvq_prep(
    const float* __restrict__ cb, short* __restrict__ cbh,
    short* __restrict__ cbl, float* __restrict__ cnorm)
{
    const int tid  = blockIdx.x * 256 + threadIdx.x;   // 16384 threads
    const int code = tid >> 4;
    const int c16  = tid & 15;
    float4 v = *(const float4*)(cb + (size_t)code * DIM + c16 * 4);
    float s = fmaf(v.x, v.x, fmaf(v.y, v.y, fmaf(v.z, v.z, v.w * v.w)));
#pragma unroll
    for (int o = 1; o < 16; o <<= 1) s += __shfl_xor(s, o, 64);

    unsigned short h0 = (unsigned short)f2bf(v.x), h1 = (unsigned short)f2bf(v.y);
    unsigned short h2 = (unsigned short)f2bf(v.z), h3 = (unsigned short)f2bf(v.w);
    unsigned short l0 = (unsigned short)f2bf(v.x - bf2f((short)h0));
    unsigned short l1 = (unsigned short)f2bf(v.y - bf2f((short)h1));
    unsigned short l2 = (unsigned short)f2bf(v.z - bf2f((short)h2));
    unsigned short l3 = (unsigned short)f2bf(v.w - bf2f((short)h3));
    uint2 hp = { (unsigned)h0 | ((unsigned)h1 << 16), (unsigned)h2 | ((unsigned)h3 << 16) };
    uint2 lp = { (unsigned)l0 | ((unsigned)l1 << 16), (unsigned)l2 | ((unsigned)l3 << 16) };
    *(uint2*)(cbh + (size_t)code * DIM + c16 * 4) = hp;
    *(uint2*)(cbl + (size_t)code * DIM + c16 * 4) = lp;
    if (c16 == 0) cnorm[code] = s;
}

// --- fused main ----------------------------------------------------------
// block = 4 waves, 128 rows; wave = 32 rows (2 rowsets of 16).
// K staged in 8 chunks of 128 codes: ldsH/ldsL 16 KB each, u-major layout:
//   16B unit (c, u) at short index u*1024 + c*8   (u = dim-octet 0..7)
// so B-frag reads (lane(q,n): codes t*16+n, u=q / q+4) are conflict-free.
__global__ __launch_bounds__(256, 4) void nsvq_fused(
    const float* __restrict__ x, const float* __restrict__ rv,
    const float* __restrict__ cb,
    const short* __restrict__ cbh, const short* __restrict__ cbl,
    const float* __restrict__ cnorm,
    float* __restrict__ out, unsigned int* __restrict__ counts)
{
    __shared__ short ldsH[8192];   // 16 KB
    __shared__ short ldsL[8192];   // 16 KB

    const int tid  = threadIdx.x;
    const int lane = tid & 63;
    const int wave = tid >> 6;
    const int q    = lane >> 4;     // 0..3: k-octet group
    const int n    = lane & 15;     // A row / B code-col
    const int waveRow = blockIdx.x * 128 + wave * 32;

    // ---- A fragments: x rows as bf16 hi/lo, [rowset][kchunk] ----
    bf16x8 ah[2][2], al[2][2];
#pragma unroll
    for (int s = 0; s < 2; ++s) {
        const int row = waveRow + s * 16 + n;
#pragma unroll
        for (int c2 = 0; c2 < 2; ++c2) {
            const float* p = x + (size_t)row * DIM + c2 * 32 + q * 8;
            float4 f0 = *(const float4*)p;
            float4 f1 = *(const float4*)(p + 4);
            float fv[8] = {f0.x, f0.y, f0.z, f0.w, f1.x, f1.y, f1.z, f1.w};
#pragma unroll
            for (int j = 0; j < 8; ++j) {
                short hi = f2bf(fv[j]);
                ah[s][c2][j] = hi;
                al[s][c2][j] = f2bf(fv[j] - bf2f(hi));
            }
        }
    }

    float best[2][4];
    int   bidx[2][4];
#pragma unroll
    for (int s = 0; s < 2; ++s)
#pragma unroll
        for (int r = 0; r < 4; ++r) { best[s][r] = 3.4e38f; bidx[s][r] = 0; }

    for (int chunk = 0; chunk < 8; ++chunk) {
        // ---- stage 128 codes (hi+lo) into LDS, u-major swizzle ----
#pragma unroll
        for (int r = 0; r < 4; ++r) {
            const int s_ = r * 256 + tid;           // 16B-unit slot 0..1023
            const int u  = s_ >> 7;
            const int c  = s_ & 127;
            const size_t goff = (size_t)(chunk * 128 + c) * DIM + u * 8;
            gl_lds16(cbh + goff, ldsH + s_ * 8);
        }
#pragma unroll
        for (int r = 0; r < 4; ++r) {
            const int s_ = r * 256 + tid;
            const int u  = s_ >> 7;
            const int c  = s_ & 127;
            const size_t goff = (size_t)(chunk * 128 + c) * DIM + u * 8;
            gl_lds16(cbl + goff, ldsL + s_ * 8);
        }
        // cnorm for this lane's 8 tiles (independent of LDS)
        float cn[8];
#pragma unroll
        for (int t = 0; t < 8; ++t) cn[t] = cnorm[chunk * 128 + t * 16 + n];

        __syncthreads();

#pragma unroll
        for (int t = 0; t < 8; ++t) {
            const int ci = (t * 16 + n) * 8;
            bf16x8 bh0 = *(const bf16x8*)(ldsH + q * 1024 + ci);
            bf16x8 bh1 = *(const bf16x8*)(ldsH + (q + 4) * 1024 + ci);
            bf16x8 bl0 = *(const bf16x8*)(ldsL + q * 1024 + ci);
            bf16x8 bl1 = *(const bf16x8*)(ldsL + (q + 4) * 1024 + ci);

            f32x4 acc[2][2];
#pragma unroll
            for (int s = 0; s < 2; ++s) {
                acc[s][0] = (f32x4){0.f, 0.f, 0.f, 0.f};
                acc[s][1] = (f32x4){0.f, 0.f, 0.f, 0.f};
                acc[s][0] = __builtin_amdgcn_mfma_f32_16x16x32_bf16(ah[s][0], bh0, acc[s][0], 0, 0, 0);
                acc[s][1] = __builtin_amdgcn_mfma_f32_16x16x32_bf16(ah[s][1], bh1, acc[s][1], 0, 0, 0);
                acc[s][0] = __builtin_amdgcn_mfma_f32_16x16x32_bf16(al[s][0], bh0, acc[s][0], 0, 0, 0);
                acc[s][1] = __builtin_amdgcn_mfma_f32_16x16x32_bf16(al[s][1], bh1, acc[s][1], 0, 0, 0);
                acc[s][0] = __builtin_amdgcn_mfma_f32_16x16x32_bf16(ah[s][0], bl0, acc[s][0], 0, 0, 0);
                acc[s][1] = __builtin_amdgcn_mfma_f32_16x16x32_bf16(ah[s][1], bl1, acc[s][1], 0, 0, 0);
            }

            const int code = chunk * 128 + t * 16 + n;
#pragma unroll
            for (int s = 0; s < 2; ++s)
#pragma unroll
                for (int r = 0; r < 4; ++r) {
                    float d = fmaf(-2.f, acc[s][0][r] + acc[s][1][r], cn[t]);
                    if (d < best[s][r]) { best[s][r] = d; bidx[s][r] = code; }
                }
        }
        __syncthreads();
    }

    // ---- argmin across the 16 code-lanes (low 4 bits of lane) ----
#pragma unroll
    for (int o = 1; o < 16; o <<= 1) {
#pragma unroll
        for (int s = 0; s < 2; ++s)
#pragma unroll
            for (int r = 0; r < 4; ++r) {
                float od = __shfl_xor(best[s][r], o, 64);
                int   ok = __shfl_xor(bidx[s][r], o, 64);
                if (od < best[s][r] || (od == best[s][r] && ok < bidx[s][r])) {
                    best[s][r] = od; bidx[s][r] = ok;
                }
            }
    }
    // now every lane holds the winner for row = waveRow + s*16 + q*4 + r

    // ---- fused epilogue: exact fp32 residual + output + histogram ----
#pragma unroll
    for (int s = 0; s < 2; ++s)
#pragma unroll
        for (int r = 0; r < 4; ++r) {
            const int row = waveRow + s * 16 + q * 4 + r;
            const size_t off = (size_t)row * DIM + n * 4;
            float4 xv  = *(const float4*)(x + off);
            float4 rvv = *(const float4*)(rv + off);
            const int bk = bidx[s][r];
            float4 cv = *(const float4*)(cb + (size_t)bk * DIM + n * 4);

            float d0 = xv.x - cv.x, d1 = xv.y - cv.y, d2 = xv.z - cv.z, d3 = xv.w - cv.w;
            float res = fmaf(d0, d0, fmaf(d1, d1, fmaf(d2, d2, d3 * d3)));
            float rr  = fmaf(rvv.x, rvv.x, fmaf(rvv.y, rvv.y, fmaf(rvv.z, rvv.z, rvv.w * rvv.w)));
#pragma unroll
            for (int o = 1; o < 16; o <<= 1) {
                res += __shfl_xor(res, o, 64);
                rr  += __shfl_xor(rr, o, 64);
            }
            float scale = sqrtf(res) / (sqrtf(rr) + 1e-12f);

            float4 ov;
            ov.x = fmaf(scale, rvv.x, xv.x);
            ov.y = fmaf(scale, rvv.y, xv.y);
            ov.z = fmaf(scale, rvv.z, xv.z);
            ov.w = fmaf(scale, rvv.w, xv.w);
            *(float4*)(out + off) = ov;

            if (n == 0) atomicAdd(&counts[bk], 1u);
        }
}

// --- finalize: perplexity + counts output --------------------------------
__global__ void nsvq_finalize(const unsigned int* __restrict__ counts,
                              const int* __restrict__ used,
                              float* __restrict__ out)
{
    const int k = threadIdx.x;  // 1024 threads
    const unsigned c = counts[k];
    float avg = (float)c * (1.0f / (float)NROWS);
    float term = (c > 0) ? (-avg * logf(avg + 1e-12f)) : 0.0f;

    float v = term;
#pragma unroll
    for (int o = 32; o > 0; o >>= 1) v += __shfl_down(v, o, 64);

    __shared__ float partial[16];
    if ((threadIdx.x & 63) == 0) partial[threadIdx.x >> 6] = v;
    __syncthreads();

    if (threadIdx.x < 64) {
        float s = (threadIdx.x < 16) ? partial[threadIdx.x] : 0.0f;
#pragma unroll
        for (int o = 32; o > 0; o >>= 1) s += __shfl_down(s, o, 64);
        if (threadIdx.x == 0) out[ND] = expf(s);
    }
    out[ND + 1 + k] = (float)(c + (unsigned)used[k]);
}

extern "C" void kernel_launch(void* const* d_in, const int* in_sizes, int n_in,
                              void* d_out, int out_size, void* d_ws, size_t ws_size,
                              hipStream_t stream) {
    const float* x    = (const float*)d_in[0];
    const float* rv   = (const float*)d_in[1];
    const float* cb   = (const float*)d_in[2];
    const int*   used = (const int*)d_in[3];
    float* out = (float*)d_out;

    char* ws = (char*)d_ws;
    unsigned int* counts = (unsigned int*)ws;                 // 4 KB
    float*        cnorm  = (float*)(ws + 4096);               // 4 KB
    short*        cbh    = (short*)(ws + 8192);               // 128 KB
    short*        cbl    = (short*)(ws + 8192 + 131072);      // 128 KB

    hipMemsetAsync(counts, 0, KCODES * sizeof(unsigned int), stream);
    nsvq_prep<<<KCODES * 16 / 256, 256, 0, stream>>>(cb, cbh, cbl, cnorm);
    nsvq_fused<<<NROWS / 128, 256, 0, stream>>>(x, rv, cb, cbh, cbl, cnorm, out, counts);
    nsvq_finalize<<<1, KCODES, 0, stream>>>(counts, used, out);
}

// Round 4
// 314.097 us; speedup vs baseline: 2.8552x; 2.8552x over previous
//
#include <hip/hip_runtime.h>
#include <math.h>

// NSVQ: N=262144 rows, D=64, K=1024 codebooks.
// d_out (fp32): [N*D] quantized | [1] perplexity | [K] counts_new.
//
// d_k = ||c_k||^2 - 2 x.c_k, computed as MFMA(C-init=||c||^2, B=-2c in bf16
// hi/lo split, 3 passes). Prep writes B pre-swizzled (u-major per 128-code
// chunk) so global_load_lds staging is lane-contiguous (16 B/lane) AND the
// LDS B-frag ds_read_b128 pattern is 2-way/bank (free). Epilogue recomputes
// ||x - c_best||^2 in exact fp32 (separate, coalesced, memory-bound kernel).

#define NROWS 262144
#define DIM 64
#define KCODES 1024
#define ND ((size_t)NROWS * DIM)

typedef __attribute__((ext_vector_type(8))) short bf16x8;   // 8 bf16, 4 VGPRs
typedef __attribute__((ext_vector_type(4))) float f32x4;

__device__ inline short f2bf(float f) {             // RNE fp32 -> bf16
    unsigned u = __builtin_bit_cast(unsigned, f);
    unsigned r = (u + 0x7FFFu + ((u >> 16) & 1u)) >> 16;
    return (short)r;
}
__device__ inline float bf2f(short h) {
    unsigned u = ((unsigned)(unsigned short)h) << 16;
    return __builtin_bit_cast(float, u);
}

typedef const __attribute__((address_space(1))) void* as1p;
typedef __attribute__((address_space(3))) void* as3p;
__device__ inline void gl_lds16(const void* g, void* l) {
    __builtin_amdgcn_global_load_lds((as1p)g, (as3p)l, 16, 0, 0);
}

// --- prep: build swizzled -2c hi/lo + fp32 norms ------------------------
// Layout of cbs (shorts): per chunk c0=k>>7 (32 KB each):
//   hi unit (u=j>>3, c=k&127) at c0*16384 + u*1024 + c*8   (+8192 for lo)
// 8192 threads: one (code k, dim-octet u) per thread.
__global__ __launch_bounds__(256) void nsvq_prep(
    const float* __restrict__ cb, short* __restrict__ cbs,
    float* __restrict__ cnorm)
{
    const int tid = blockIdx.x * 256 + threadIdx.x;   // 8192
    const int k = tid >> 3;
    const int u = tid & 7;
    const float* p = cb + (size_t)k * DIM + u * 8;
    float4 f0 = *(const float4*)p;
    float4 f1 = *(const float4*)(p + 4);
    float fv[8] = {f0.x, f0.y, f0.z, f0.w, f1.x, f1.y, f1.z, f1.w};

    float s = 0.f;
    bf16x8 hv, lv;
#pragma unroll
    for (int j = 0; j < 8; ++j) {
        s = fmaf(fv[j], fv[j], s);
        float f = -2.0f * fv[j];
        short hi = f2bf(f);
        hv[j] = hi;
        lv[j] = f2bf(f - bf2f(hi));
    }
    // norm reduce across the 8 u-lanes (consecutive lanes of the wave)
#pragma unroll
    for (int o = 1; o < 8; o <<= 1) s += __shfl_xor(s, o, 64);

    const size_t base = (size_t)(k >> 7) * 16384 + (size_t)u * 1024 + (size_t)(k & 127) * 8;
    *(bf16x8*)(cbs + base) = hv;
    *(bf16x8*)(cbs + base + 8192) = lv;
    if (u == 0) cnorm[k] = s;
}

// --- main: MFMA distances + per-row argmin ------------------------------
// block = 4 waves = 256 rows; wave = 64 rows (4 rowsets of 16).
// Per chunk: contiguous 32 KB global_load_lds stage, then 8 tiles of 16
// codes; 24 MFMA per tile (4 rowsets x (3 terms x 2 k-chunks)).
__global__ __launch_bounds__(256) void nsvq_mfma(
    const float* __restrict__ x, const short* __restrict__ cbs,
    const float* __restrict__ cnorm, int* __restrict__ bestk_out)
{
    __shared__ short lds[16384];   // 32 KB: hi [0,8192) lo [8192,16384)

    const int tid  = threadIdx.x;
    const int lane = tid & 63;
    const int wave = tid >> 6;
    const int q    = lane >> 4;     // k-octet group 0..3
    const int n    = lane & 15;     // A row / B code-col
    const int wBase = blockIdx.x * 256 + wave * 64;

    // A fragments: x rows, bf16 hi/lo (unscaled)
    bf16x8 ah[4][2], al[4][2];
#pragma unroll
    for (int s = 0; s < 4; ++s) {
        const int row = wBase + s * 16 + n;
#pragma unroll
        for (int c2 = 0; c2 < 2; ++c2) {
            const float* p = x + (size_t)row * DIM + c2 * 32 + q * 8;
            float4 g0 = *(const float4*)p;
            float4 g1 = *(const float4*)(p + 4);
            float fv[8] = {g0.x, g0.y, g0.z, g0.w, g1.x, g1.y, g1.z, g1.w};
#pragma unroll
            for (int j = 0; j < 8; ++j) {
                short hi = f2bf(fv[j]);
                ah[s][c2][j] = hi;
                al[s][c2][j] = f2bf(fv[j] - bf2f(hi));
            }
        }
    }

    float best[4][4];
    int   bidx[4][4];
#pragma unroll
    for (int s = 0; s < 4; ++s)
#pragma unroll
        for (int r = 0; r < 4; ++r) { best[s][r] = 3.4e38f; bidx[s][r] = 0; }

    for (int chunk = 0; chunk < 8; ++chunk) {
        // contiguous stage: 8 x (256 lanes x 16 B) = 32 KB
        const short* src = cbs + (size_t)chunk * 16384;
#pragma unroll
        for (int r = 0; r < 8; ++r) {
            const int idx = r * 256 + tid;
            gl_lds16(src + idx * 8, lds + idx * 8);
        }
        float cn[8];
#pragma unroll
        for (int t = 0; t < 8; ++t) cn[t] = cnorm[chunk * 128 + t * 16 + n];

        __syncthreads();

#pragma unroll
        for (int t = 0; t < 8; ++t) {
            const int ci = (t * 16 + n) * 8;
            bf16x8 bh0 = *(const bf16x8*)(lds + q * 1024 + ci);
            bf16x8 bh1 = *(const bf16x8*)(lds + (q + 4) * 1024 + ci);
            bf16x8 bl0 = *(const bf16x8*)(lds + 8192 + q * 1024 + ci);
            bf16x8 bl1 = *(const bf16x8*)(lds + 8192 + (q + 4) * 1024 + ci);
            f32x4 cnv = {cn[t], cn[t], cn[t], cn[t]};
            const int code = chunk * 128 + t * 16 + n;

#pragma unroll
            for (int s = 0; s < 4; ++s) {
                f32x4 a = cnv;   // C-init = ||c||^2; B = -2c => acc = distance
                a = __builtin_amdgcn_mfma_f32_16x16x32_bf16(ah[s][0], bh0, a, 0, 0, 0);
                a = __builtin_amdgcn_mfma_f32_16x16x32_bf16(ah[s][1], bh1, a, 0, 0, 0);
                a = __builtin_amdgcn_mfma_f32_16x16x32_bf16(al[s][0], bh0, a, 0, 0, 0);
                a = __builtin_amdgcn_mfma_f32_16x16x32_bf16(al[s][1], bh1, a, 0, 0, 0);
                a = __builtin_amdgcn_mfma_f32_16x16x32_bf16(ah[s][0], bl0, a, 0, 0, 0);
                a = __builtin_amdgcn_mfma_f32_16x16x32_bf16(ah[s][1], bl1, a, 0, 0, 0);
#pragma unroll
                for (int r = 0; r < 4; ++r) {
                    if (a[r] < best[s][r]) { best[s][r] = a[r]; bidx[s][r] = code; }
                }
            }
        }
        __syncthreads();
    }

    // argmin across the 16 code-lanes
#pragma unroll
    for (int o = 1; o < 16; o <<= 1) {
#pragma unroll
        for (int s = 0; s < 4; ++s)
#pragma unroll
            for (int r = 0; r < 4; ++r) {
                float od = __shfl_xor(best[s][r], o, 64);
                int   ok = __shfl_xor(bidx[s][r], o, 64);
                if (od < best[s][r] || (od == best[s][r] && ok < bidx[s][r])) {
                    best[s][r] = od; bidx[s][r] = ok;
                }
            }
    }
    if (n == 0) {
#pragma unroll
        for (int s = 0; s < 4; ++s)
#pragma unroll
            for (int r = 0; r < 4; ++r)
                bestk_out[wBase + s * 16 + q * 4 + r] = bidx[s][r];
    }
}

// --- epilogue: exact fp32 residual + NSVQ output + histogram ------------
__global__ __launch_bounds__(256) void nsvq_epilogue(
    const float* __restrict__ x, const float* __restrict__ rv,
    const float* __restrict__ cb, const int* __restrict__ bestk_in,
    float* __restrict__ out, unsigned int* __restrict__ counts)
{
    const int lane = threadIdx.x & 63;
    const int wave = threadIdx.x >> 6;
    const int sub = lane >> 4;
    const int c16 = lane & 15;
    const int row = (blockIdx.x * 4 + wave) * 4 + sub;
    const size_t off = (size_t)row * DIM + c16 * 4;

    float4 xv  = *(const float4*)(x + off);
    float4 rvv = *(const float4*)(rv + off);
    const int bk = bestk_in[row];
    float4 cv = *(const float4*)(cb + (size_t)bk * DIM + c16 * 4);

    float d0 = xv.x - cv.x, d1 = xv.y - cv.y, d2 = xv.z - cv.z, d3 = xv.w - cv.w;
    float res = fmaf(d0, d0, fmaf(d1, d1, fmaf(d2, d2, d3 * d3)));
    float rr  = fmaf(rvv.x, rvv.x, fmaf(rvv.y, rvv.y, fmaf(rvv.z, rvv.z, rvv.w * rvv.w)));
#pragma unroll
    for (int o = 1; o < 16; o <<= 1) {
        res += __shfl_xor(res, o, 64);
        rr  += __shfl_xor(rr, o, 64);
    }
    float scale = sqrtf(res) / (sqrtf(rr) + 1e-12f);

    float4 ov;
    ov.x = fmaf(scale, rvv.x, xv.x);
    ov.y = fmaf(scale, rvv.y, xv.y);
    ov.z = fmaf(scale, rvv.z, xv.z);
    ov.w = fmaf(scale, rvv.w, xv.w);
    *(float4*)(out + off) = ov;

    if (c16 == 0) atomicAdd(&counts[bk], 1u);
}

// --- finalize: perplexity + counts output -------------------------------
__global__ void nsvq_finalize(const unsigned int* __restrict__ counts,
                              const int* __restrict__ used,
                              float* __restrict__ out)
{
    const int k = threadIdx.x;  // 1024 threads
    const unsigned c = counts[k];
    float avg = (float)c * (1.0f / (float)NROWS);
    float term = (c > 0) ? (-avg * logf(avg + 1e-12f)) : 0.0f;

    float v = term;
#pragma unroll
    for (int o = 32; o > 0; o >>= 1) v += __shfl_down(v, o, 64);

    __shared__ float partial[16];
    if ((threadIdx.x & 63) == 0) partial[threadIdx.x >> 6] = v;
    __syncthreads();

    if (threadIdx.x < 64) {
        float s = (threadIdx.x < 16) ? partial[threadIdx.x] : 0.0f;
#pragma unroll
        for (int o = 32; o > 0; o >>= 1) s += __shfl_down(s, o, 64);
        if (threadIdx.x == 0) out[ND] = expf(s);
    }
    out[ND + 1 + k] = (float)(c + (unsigned)used[k]);
}

extern "C" void kernel_launch(void* const* d_in, const int* in_sizes, int n_in,
                              void* d_out, int out_size, void* d_ws, size_t ws_size,
                              hipStream_t stream) {
    const float* x    = (const float*)d_in[0];
    const float* rv   = (const float*)d_in[1];
    const float* cb   = (const float*)d_in[2];
    const int*   used = (const int*)d_in[3];
    float* out = (float*)d_out;

    char* ws = (char*)d_ws;
    unsigned int* counts = (unsigned int*)ws;                 // 4 KB
    float*        cnorm  = (float*)(ws + 4096);               // 4 KB
    short*        cbs    = (short*)(ws + 8192);               // 256 KB swizzled -2c hi/lo
    int*          bestk  = (int*)(ws + 8192 + 262144);        // 1 MB

    hipMemsetAsync(counts, 0, KCODES * sizeof(unsigned int), stream);
    nsvq_prep<<<KCODES * 8 / 256, 256, 0, stream>>>(cb, cbs, cnorm);
    nsvq_mfma<<<NROWS / 256, 256, 0, stream>>>(x, cbs, cnorm, bestk);
    nsvq_epilogue<<<NROWS / 16, 256, 0, stream>>>(x, rv, cb, bestk, out, counts);
    nsvq_finalize<<<1, KCODES, 0, stream>>>(counts, used, out);
}

// Round 5
// 269.982 us; speedup vs baseline: 3.3217x; 1.1634x over previous
//
#include <hip/hip_runtime.h>
#include <math.h>

// NSVQ: N=262144 rows, D=64, K=1024 codebooks.
// d_out (fp32): [N*D] quantized | [1] perplexity | [K] counts_new.
//
// Fully fused main kernel: d_k = MFMA(C-init=||c||^2, B=-2c bf16 hi/lo, 3
// passes) -> per-row argmin -> res^2 = ||x||^2 + d_best (error ~1e-4 abs on
// ~64: negligible) -> NSVQ output + histogram, all in one pass over x/rv.
// Codebook pre-swizzled by prep so global_load_lds staging is lane-contiguous
// and LDS B-frag ds_read_b128 is conflict-free.

#define NROWS 262144
#define DIM 64
#define KCODES 1024
#define ND ((size_t)NROWS * DIM)

typedef __attribute__((ext_vector_type(8))) short bf16x8;   // 8 bf16, 4 VGPRs
typedef __attribute__((ext_vector_type(4))) float f32x4;

__device__ inline short f2bf(float f) {             // RNE fp32 -> bf16
    unsigned u = __builtin_bit_cast(unsigned, f);
    unsigned r = (u + 0x7FFFu + ((u >> 16) & 1u)) >> 16;
    return (short)r;
}
__device__ inline float bf2f(short h) {
    unsigned u = ((unsigned)(unsigned short)h) << 16;
    return __builtin_bit_cast(float, u);
}

typedef const __attribute__((address_space(1))) void* as1p;
typedef __attribute__((address_space(3))) void* as3p;
__device__ inline void gl_lds16(const void* g, void* l) {
    __builtin_amdgcn_global_load_lds((as1p)g, (as3p)l, 16, 0, 0);
}

// --- prep: build swizzled -2c hi/lo + fp32 norms ------------------------
// cbs layout (shorts): chunk c0=k>>7 (32 KB each):
//   hi unit (u=j>>3, c=k&127) at c0*16384 + u*1024 + c*8   (+8192 for lo)
__global__ __launch_bounds__(256) void nsvq_prep(
    const float* __restrict__ cb, short* __restrict__ cbs,
    float* __restrict__ cnorm)
{
    const int tid = blockIdx.x * 256 + threadIdx.x;   // 8192
    const int k = tid >> 3;
    const int u = tid & 7;
    const float* p = cb + (size_t)k * DIM + u * 8;
    float4 f0 = *(const float4*)p;
    float4 f1 = *(const float4*)(p + 4);
    float fv[8] = {f0.x, f0.y, f0.z, f0.w, f1.x, f1.y, f1.z, f1.w};

    float s = 0.f;
    bf16x8 hv, lv;
#pragma unroll
    for (int j = 0; j < 8; ++j) {
        s = fmaf(fv[j], fv[j], s);
        float f = -2.0f * fv[j];
        short hi = f2bf(f);
        hv[j] = hi;
        lv[j] = f2bf(f - bf2f(hi));
    }
#pragma unroll
    for (int o = 1; o < 8; o <<= 1) s += __shfl_xor(s, o, 64);

    const size_t base = (size_t)(k >> 7) * 16384 + (size_t)u * 1024 + (size_t)(k & 127) * 8;
    *(bf16x8*)(cbs + base) = hv;
    *(bf16x8*)(cbs + base + 8192) = lv;
    if (u == 0) cnorm[k] = s;
}

// --- fused main ---------------------------------------------------------
// block = 4 waves = 128 rows; wave = 32 rows (2 rowsets of 16).
// lane = (q = k-octet 0..3, n = row/code-col 0..15).
__global__ __launch_bounds__(256) void nsvq_fused(
    const float* __restrict__ x, const float* __restrict__ rv,
    const short* __restrict__ cbs, const float* __restrict__ cnorm,
    float* __restrict__ out, unsigned int* __restrict__ counts)
{
    __shared__ short lds[16384];   // 32 KB: hi [0,8192) lo [8192,16384)

    const int tid  = threadIdx.x;
    const int lane = tid & 63;
    const int wave = tid >> 6;
    const int q    = lane >> 4;
    const int n    = lane & 15;
    const int wBase = blockIdx.x * 128 + wave * 32;

    // ---- A: x rows fp32-resident + bf16 hi/lo frags + ||x||^2 ----
    float  xf[2][16];
    bf16x8 ah[2][2], al[2][2];
    float  xx[2];
#pragma unroll
    for (int s = 0; s < 2; ++s) {
        const int row = wBase + s * 16 + n;
        float acc = 0.f;
#pragma unroll
        for (int c2 = 0; c2 < 2; ++c2) {
            const float* p = x + (size_t)row * DIM + c2 * 32 + q * 8;
            float4 g0 = *(const float4*)p;
            float4 g1 = *(const float4*)(p + 4);
            xf[s][c2 * 8 + 0] = g0.x; xf[s][c2 * 8 + 1] = g0.y;
            xf[s][c2 * 8 + 2] = g0.z; xf[s][c2 * 8 + 3] = g0.w;
            xf[s][c2 * 8 + 4] = g1.x; xf[s][c2 * 8 + 5] = g1.y;
            xf[s][c2 * 8 + 6] = g1.z; xf[s][c2 * 8 + 7] = g1.w;
#pragma unroll
            for (int j = 0; j < 8; ++j) {
                float f = xf[s][c2 * 8 + j];
                acc = fmaf(f, f, acc);
                short hi = f2bf(f);
                ah[s][c2][j] = hi;
                al[s][c2][j] = f2bf(f - bf2f(hi));
            }
        }
        // reduce over the 4 q-lanes holding this row (lane bits 4,5)
        acc += __shfl_xor(acc, 16, 64);
        acc += __shfl_xor(acc, 32, 64);
        xx[s] = acc;
    }

    float best[2][4];
    int   bidx[2][4];
#pragma unroll
    for (int s = 0; s < 2; ++s)
#pragma unroll
        for (int r = 0; r < 4; ++r) { best[s][r] = 3.4e38f; bidx[s][r] = 0; }

    for (int chunk = 0; chunk < 8; ++chunk) {
        const short* src = cbs + (size_t)chunk * 16384;
#pragma unroll
        for (int r = 0; r < 8; ++r) {
            const int idx = r * 256 + tid;       // lane-contiguous 16 B/lane
            gl_lds16(src + idx * 8, lds + idx * 8);
        }
        float cn[8];
#pragma unroll
        for (int t = 0; t < 8; ++t) cn[t] = cnorm[chunk * 128 + t * 16 + n];

        __syncthreads();

#pragma unroll
        for (int t = 0; t < 8; ++t) {
            const int ci = (t * 16 + n) * 8;
            bf16x8 bh0 = *(const bf16x8*)(lds + q * 1024 + ci);
            bf16x8 bh1 = *(const bf16x8*)(lds + (q + 4) * 1024 + ci);
            bf16x8 bl0 = *(const bf16x8*)(lds + 8192 + q * 1024 + ci);
            bf16x8 bl1 = *(const bf16x8*)(lds + 8192 + (q + 4) * 1024 + ci);
            f32x4 cnv = {cn[t], cn[t], cn[t], cn[t]};
            const int code = chunk * 128 + t * 16 + n;

#pragma unroll
            for (int s = 0; s < 2; ++s) {
                f32x4 a = cnv;   // C-init = ||c||^2; B = -2c => acc = distance
                a = __builtin_amdgcn_mfma_f32_16x16x32_bf16(ah[s][0], bh0, a, 0, 0, 0);
                a = __builtin_amdgcn_mfma_f32_16x16x32_bf16(ah[s][1], bh1, a, 0, 0, 0);
                a = __builtin_amdgcn_mfma_f32_16x16x32_bf16(al[s][0], bh0, a, 0, 0, 0);
                a = __builtin_amdgcn_mfma_f32_16x16x32_bf16(al[s][1], bh1, a, 0, 0, 0);
                a = __builtin_amdgcn_mfma_f32_16x16x32_bf16(ah[s][0], bl0, a, 0, 0, 0);
                a = __builtin_amdgcn_mfma_f32_16x16x32_bf16(ah[s][1], bl1, a, 0, 0, 0);
#pragma unroll
                for (int r = 0; r < 4; ++r) {
                    if (a[r] < best[s][r]) { best[s][r] = a[r]; bidx[s][r] = code; }
                }
            }
        }
        __syncthreads();
    }

    // ---- argmin across the 16 code-lanes ----
#pragma unroll
    for (int o = 1; o < 16; o <<= 1) {
#pragma unroll
        for (int s = 0; s < 2; ++s)
#pragma unroll
            for (int r = 0; r < 4; ++r) {
                float od = __shfl_xor(best[s][r], o, 64);
                int   ok = __shfl_xor(bidx[s][r], o, 64);
                if (od < best[s][r] || (od == best[s][r] && ok < bidx[s][r])) {
                    best[s][r] = od; bidx[s][r] = ok;
                }
            }
    }
    // lane (q,*) now holds winners for rows s*16 + q*4 + r.

    // ---- route per-row best through LDS (winner lanes -> row lanes) ----
    float* resf = (float*)lds;   // 128 floats, reuse staging buffer
    if (n == 0) {
#pragma unroll
        for (int s = 0; s < 2; ++s)
#pragma unroll
            for (int r = 0; r < 4; ++r) {
                const int rl = wave * 32 + s * 16 + q * 4 + r;
                resf[rl] = best[s][r];
                atomicAdd(&counts[bidx[s][r]], 1u);
            }
    }
    __syncthreads();

    // ---- epilogue: scale + output (lane (q,n) owns row n's dims) ----
#pragma unroll
    for (int s = 0; s < 2; ++s) {
        const int row = wBase + s * 16 + n;
        float res2 = xx[s] + resf[wave * 32 + s * 16 + n];   // broadcast read
        if (res2 < 0.f) res2 = 0.f;
        float resn = sqrtf(res2);

        float rvf[16];
        float rr = 0.f;
#pragma unroll
        for (int c2 = 0; c2 < 2; ++c2) {
            const float* p = rv + (size_t)row * DIM + c2 * 32 + q * 8;
            float4 g0 = *(const float4*)p;
            float4 g1 = *(const float4*)(p + 4);
            rvf[c2 * 8 + 0] = g0.x; rvf[c2 * 8 + 1] = g0.y;
            rvf[c2 * 8 + 2] = g0.z; rvf[c2 * 8 + 3] = g0.w;
            rvf[c2 * 8 + 4] = g1.x; rvf[c2 * 8 + 5] = g1.y;
            rvf[c2 * 8 + 6] = g1.z; rvf[c2 * 8 + 7] = g1.w;
#pragma unroll
            for (int j = 0; j < 8; ++j) {
                float f = rvf[c2 * 8 + j];
                rr = fmaf(f, f, rr);
            }
        }
        rr += __shfl_xor(rr, 16, 64);
        rr += __shfl_xor(rr, 32, 64);
        float scale = resn / (sqrtf(rr) + 1e-12f);

#pragma unroll
        for (int c2 = 0; c2 < 2; ++c2) {
            float4 o0, o1;
            o0.x = fmaf(scale, rvf[c2 * 8 + 0], xf[s][c2 * 8 + 0]);
            o0.y = fmaf(scale, rvf[c2 * 8 + 1], xf[s][c2 * 8 + 1]);
            o0.z = fmaf(scale, rvf[c2 * 8 + 2], xf[s][c2 * 8 + 2]);
            o0.w = fmaf(scale, rvf[c2 * 8 + 3], xf[s][c2 * 8 + 3]);
            o1.x = fmaf(scale, rvf[c2 * 8 + 4], xf[s][c2 * 8 + 4]);
            o1.y = fmaf(scale, rvf[c2 * 8 + 5], xf[s][c2 * 8 + 5]);
            o1.z = fmaf(scale, rvf[c2 * 8 + 6], xf[s][c2 * 8 + 6]);
            o1.w = fmaf(scale, rvf[c2 * 8 + 7], xf[s][c2 * 8 + 7]);
            float* op = out + (size_t)row * DIM + c2 * 32 + q * 8;
            *(float4*)op = o0;
            *(float4*)(op + 4) = o1;
        }
    }
}

// --- finalize: perplexity + counts output -------------------------------
__global__ void nsvq_finalize(const unsigned int* __restrict__ counts,
                              const int* __restrict__ used,
                              float* __restrict__ out)
{
    const int k = threadIdx.x;  // 1024 threads
    const unsigned c = counts[k];
    float avg = (float)c * (1.0f / (float)NROWS);
    float term = (c > 0) ? (-avg * logf(avg + 1e-12f)) : 0.0f;

    float v = term;
#pragma unroll
    for (int o = 32; o > 0; o >>= 1) v += __shfl_down(v, o, 64);

    __shared__ float partial[16];
    if ((threadIdx.x & 63) == 0) partial[threadIdx.x >> 6] = v;
    __syncthreads();

    if (threadIdx.x < 64) {
        float s = (threadIdx.x < 16) ? partial[threadIdx.x] : 0.0f;
#pragma unroll
        for (int o = 32; o > 0; o >>= 1) s += __shfl_down(s, o, 64);
        if (threadIdx.x == 0) out[ND] = expf(s);
    }
    out[ND + 1 + k] = (float)(c + (unsigned)used[k]);
}

extern "C" void kernel_launch(void* const* d_in, const int* in_sizes, int n_in,
                              void* d_out, int out_size, void* d_ws, size_t ws_size,
                              hipStream_t stream) {
    const float* x    = (const float*)d_in[0];
    const float* rv   = (const float*)d_in[1];
    const float* cb   = (const float*)d_in[2];
    const int*   used = (const int*)d_in[3];
    float* out = (float*)d_out;

    char* ws = (char*)d_ws;
    unsigned int* counts = (unsigned int*)ws;                 // 4 KB
    float*        cnorm  = (float*)(ws + 4096);               // 4 KB
    short*        cbs    = (short*)(ws + 8192);               // 256 KB swizzled -2c hi/lo

    hipMemsetAsync(counts, 0, KCODES * sizeof(unsigned int), stream);
    nsvq_prep<<<KCODES * 8 / 256, 256, 0, stream>>>(cb, cbs, cnorm);
    nsvq_fused<<<NROWS / 128, 256, 0, stream>>>(x, rv, cbs, cnorm, out, counts);
    nsvq_finalize<<<1, KCODES, 0, stream>>>(counts, used, out);
}